// Round 1
// baseline (18.375 us; speedup 1.0000x reference)
//
#include <hip/hip_runtime.h>

// Problem constants (N=1)
#define LRES   64
#define ATOMS  14
#define M      896      // LRES*ATOMS
#define DF     128
#define HF     64
#define CUT2   25.0f    // 5.0^2

// ws float offsets
#define U_OFF    0              // 128
#define V_OFF    128            // 128
#define SB_OFF   256            // 1
#define SIW_OFF  320            // 896
#define SJW_OFF  (320 + 896)    // 896
#define SIM_OFF  (320 + 2*896)  // 896
#define SJM_OFF  (320 + 3*896)  // 896
#define PART_OFF (320 + 4*896)  // 896*14 = 12544
// total 16448 floats = 65792 bytes

// Kernel 1: u[d] = sum_h W2[h]*W1[h, d];  v[d] = sum_h W2[h]*W1[h, D+d];  sb = W2·b1
__global__ void k_prep_uv(const float* __restrict__ W1, const float* __restrict__ b1,
                          const float* __restrict__ W2, float* __restrict__ ws) {
    int t = threadIdx.x;            // 256 threads: t<128 -> u, t>=128 -> v
    float s = 0.f;
    #pragma unroll
    for (int h = 0; h < HF; ++h) s += W2[h] * W1[h * (2 * DF) + t];
    ws[t] = s;                       // u at [0,128), v at [128,256)
    if (t == 0) {
        float sb = 0.f;
        #pragma unroll
        for (int h = 0; h < HF; ++h) sb += W2[h] * b1[h];
        ws[SB_OFF] = sb;
    }
}

// Kernel 2: per-row dots si = f·u, sj = f·v for wt and mut. One wave per row.
__global__ void k_prep_s(const float* __restrict__ feats_wt,
                         const float* __restrict__ feats_mut,
                         float* __restrict__ ws) {
    int i = blockIdx.x;             // 896 rows
    int t = threadIdx.x;            // 64 threads (one wave)
    const float* u = ws + U_OFF;
    const float* v = ws + V_OFF;
    float fw0 = feats_wt[i * DF + t],  fw1 = feats_wt[i * DF + 64 + t];
    float fm0 = feats_mut[i * DF + t], fm1 = feats_mut[i * DF + 64 + t];
    float u0 = u[t], u1 = u[64 + t], v0 = v[t], v1 = v[64 + t];
    float siw = fw0 * u0 + fw1 * u1;
    float sjw = fw0 * v0 + fw1 * v1;
    float sim = fm0 * u0 + fm1 * u1;
    float sjm = fm0 * v0 + fm1 * v1;
    #pragma unroll
    for (int off = 32; off > 0; off >>= 1) {
        siw += __shfl_down(siw, off);
        sjw += __shfl_down(sjw, off);
        sim += __shfl_down(sim, off);
        sjm += __shfl_down(sjm, off);
    }
    if (t == 0) {
        ws[SIW_OFF + i] = siw;
        ws[SJW_OFF + i] = sjw;
        ws[SIM_OFF + i] = sim;
        ws[SJM_OFF + i] = sjm;
    }
}

// Kernel 3: one block per atom i. Threads partition j by a2=j%14 so each
// thread owns exactly one output column -> no atomics, fixed-order reduce.
__global__ void k_pairs(const float* __restrict__ pos_wt,
                        const float* __restrict__ pos_mut,
                        const int* __restrict__ ppi_wt,
                        const int* __restrict__ ppi_mut,
                        float* __restrict__ ws) {
    int i = blockIdx.x;             // 896
    int t = threadIdx.x;            // 256, 224 active (14 cols x 16 chunks)
    __shared__ float acc[16][14];

    float pwx = pos_wt[i * 3 + 0], pwy = pos_wt[i * 3 + 1], pwz = pos_wt[i * 3 + 2];
    float pmx = pos_mut[i * 3 + 0], pmy = pos_mut[i * 3 + 1], pmz = pos_mut[i * 3 + 2];
    int cw_i = ppi_wt[i / ATOMS];
    int cm_i = ppi_mut[i / ATOMS];
    float sb = ws[SB_OFF];
    float base_w = ws[SIW_OFF + i] + sb;
    float base_m = ws[SIM_OFF + i] + sb;
    const float* sjw = ws + SJW_OFF;
    const float* sjm = ws + SJM_OFF;

    if (t < 14 * 16) {
        int a2 = t % ATOMS;
        int k  = t / ATOMS;         // 0..15
        float c = 0.f;
        for (int l2 = k; l2 < LRES; l2 += 16) {
            int j = l2 * ATOMS + a2;
            if (ppi_wt[l2] != cw_i) {
                float dx = pwx - pos_wt[j * 3 + 0];
                float dy = pwy - pos_wt[j * 3 + 1];
                float dz = pwz - pos_wt[j * 3 + 2];
                float d2 = dx * dx + dy * dy + dz * dz;
                if (d2 < CUT2) c -= base_w + sjw[j];
            }
            if (ppi_mut[l2] != cm_i) {
                float dx = pmx - pos_mut[j * 3 + 0];
                float dy = pmy - pos_mut[j * 3 + 1];
                float dz = pmz - pos_mut[j * 3 + 2];
                float d2 = dx * dx + dy * dy + dz * dz;
                if (d2 < CUT2) c += base_m + sjm[j];
            }
        }
        acc[k][a2] = c;
    }
    __syncthreads();
    if (t < ATOMS) {
        float s = 0.f;
        #pragma unroll
        for (int k = 0; k < 16; ++k) s += acc[k][t];
        ws[PART_OFF + i * ATOMS + t] = s;
    }
}

// Kernel 4: out[a1*14+a2] = sum over l1 of partial[(l1*14+a1)*14 + a2] + b2
__global__ void k_final(const float* __restrict__ b2, const float* __restrict__ ws,
                        float* __restrict__ out) {
    int t = threadIdx.x;            // 256, 196 active
    if (t < ATOMS * ATOMS) {
        int a1 = t / ATOMS, a2 = t % ATOMS;
        float s = 0.f;
        #pragma unroll
        for (int l1 = 0; l1 < LRES; ++l1)
            s += ws[PART_OFF + (l1 * ATOMS + a1) * ATOMS + a2];
        out[t] = s + b2[0];
    }
}

extern "C" void kernel_launch(void* const* d_in, const int* in_sizes, int n_in,
                              void* d_out, int out_size, void* d_ws, size_t ws_size,
                              hipStream_t stream) {
    const float* feats_wt  = (const float*)d_in[0];
    const float* feats_mut = (const float*)d_in[1];
    const float* pos_wt    = (const float*)d_in[2];   // (1,64,14,3) -> (896,3)
    const float* pos_mut   = (const float*)d_in[3];
    const int*   ppi_wt    = (const int*)d_in[4];     // (1,64)
    const int*   ppi_mut   = (const int*)d_in[5];
    const float* W1        = (const float*)d_in[6];   // (64, 256)
    const float* b1        = (const float*)d_in[7];   // (64,)
    const float* W2        = (const float*)d_in[8];   // (1, 64)
    const float* b2        = (const float*)d_in[9];   // (1,)
    float* out = (float*)d_out;                       // 196 floats
    float* ws  = (float*)d_ws;

    k_prep_uv<<<1, 256, 0, stream>>>(W1, b1, W2, ws);
    k_prep_s<<<M, 64, 0, stream>>>(feats_wt, feats_mut, ws);
    k_pairs<<<M, 256, 0, stream>>>(pos_wt, pos_mut, ppi_wt, ppi_mut, ws);
    k_final<<<1, 256, 0, stream>>>(b2, ws, out);
}